// Round 12
// baseline (836.551 us; speedup 1.0000x reference)
//
#include <hip/hip_runtime.h>
#include <hip/hip_bf16.h>
#include <cstdint>

#define D_MODELX 768
#define D_STATEX 16
#define TSEQ 2048
#define BSZ 8
#define KCONV 4
#define NCAT 896          // 768 (dt) + 16 (B) + 16 (C) + 96 pad, = 7*128

typedef unsigned short ushort_t;
typedef __attribute__((ext_vector_type(8))) short short8v;   // 8 bf16 = 4 VGPR
typedef __attribute__((ext_vector_type(4))) float floatx4;

__device__ __forceinline__ unsigned short f2bf(float f) {   // RNE truncate to bf16
  unsigned int u = __float_as_uint(f);
  unsigned int r = u + 0x7FFFu + ((u >> 16) & 1u);
  return (unsigned short)(r >> 16);
}
__device__ __forceinline__ float bf2f(unsigned short s) {
  return __uint_as_float(((unsigned int)s) << 16);
}
__device__ __forceinline__ float softplus_f(float v) {
  return fmaxf(v, 0.f) + log1pf(expf(-fabsf(v)));
}
__device__ __forceinline__ void gload_lds16(const void* gsrc, void* ldst) {
  __builtin_amdgcn_global_load_lds(
      (const __attribute__((address_space(1))) unsigned int*)gsrc,
      (__attribute__((address_space(3))) unsigned int*)ldst, 16, 0, 0);
}

// ---------------- split f32 -> bf16 hi/lo ----------------
__global__ __launch_bounds__(256) void split_hl(
    const float* __restrict__ in, ushort_t* __restrict__ hi,
    ushort_t* __restrict__ lo, int n4)
{
  int i = blockIdx.x * 256 + threadIdx.x;
  if (i >= n4) return;
  float4 v = ((const float4*)in)[i];
  ushort4 h, l;
  ushort_t hb;
  hb = f2bf(v.x); h.x = hb; l.x = f2bf(v.x - bf2f(hb));
  hb = f2bf(v.y); h.y = hb; l.y = f2bf(v.y - bf2f(hb));
  hb = f2bf(v.z); h.z = hb; l.z = f2bf(v.z - bf2f(hb));
  hb = f2bf(v.w); h.w = hb; l.w = f2bf(v.w - bf2f(hb));
  ((ushort4*)hi)[i] = h;
  ((ushort4*)lo)[i] = l;
}

// ---- build concat weight [896][768]: rows 0..767 = W_dt, 768..783 = W_B, 784..799 = W_C, rest 0
__global__ __launch_bounds__(256) void split_cat(
    const float* __restrict__ Wdt, const float* __restrict__ WB,
    const float* __restrict__ WC, ushort_t* __restrict__ hi, ushort_t* __restrict__ lo)
{
  int i = blockIdx.x * 256 + threadIdx.x;          // over NCAT*768/4
  if (i >= NCAT * D_MODELX / 4) return;
  const int row = i / (D_MODELX / 4);
  const int c = (i % (D_MODELX / 4)) * 4;
  float4 v;
  if (row < 768)       v = *(const float4*)(Wdt + (size_t)row * D_MODELX + c);
  else if (row < 784)  v = *(const float4*)(WB + (size_t)(row - 768) * D_MODELX + c);
  else if (row < 800)  v = *(const float4*)(WC + (size_t)(row - 784) * D_MODELX + c);
  else                 v = make_float4(0.f, 0.f, 0.f, 0.f);
  ushort4 h, l;
  ushort_t hb;
  hb = f2bf(v.x); h.x = hb; l.x = f2bf(v.x - bf2f(hb));
  hb = f2bf(v.y); h.y = hb; l.y = f2bf(v.y - bf2f(hb));
  hb = f2bf(v.z); h.z = hb; l.z = f2bf(v.z - bf2f(hb));
  hb = f2bf(v.w); h.w = hb; l.w = f2bf(v.w - bf2f(hb));
  ((ushort4*)hi)[i] = h;
  ((ushort4*)lo)[i] = l;
}

// ---------------- bf16x3 MFMA GEMM: C[M,N] = (Ah+Al)[M,K] @ (Wh+Wl)[NW,K]^T ----------------
// 128x128 tile, BK=32, 4 waves (2x2 of 64x64).
// T3-minimum 2-phase pipeline: double-buffered LDS; next tile's global_load_lds issued
// BEFORE current tile's ds_read+MFMA; ONE __syncthreads per K-step (its vmcnt(0) drain
// lands after a full compute phase -> load latency hidden; in-flight bytes per CU ~20x).
// epi==0: plain store to C[M,N]. epi==2: mamba epilogue (dt softplus+bias / Bm / Cm split).
#define GBM 128
#define GBN 128
#define GBK 32

__global__ __launch_bounds__(256) void gemm_bf16x3(
    const ushort_t* __restrict__ Ah, const ushort_t* __restrict__ Al,
    const ushort_t* __restrict__ Wh, const ushort_t* __restrict__ Wl,
    float* __restrict__ C, int M, int N, int K,
    const float* __restrict__ bias, int epi,
    float* __restrict__ Bm, float* __restrict__ Cm)
{
  __shared__ ushort_t lds[2][4 * 4096];   // 2 x 32 KB double buffer
  const int tid = threadIdx.x;
  const int wid = tid >> 6;            // 0..3
  const int lane = tid & 63;
  const int row0 = blockIdx.y * GBM;
  const int col0 = blockIdx.x * GBN;

  // staging: wave wid owns tile wid (0:Ah 1:Al 2:Wh 3:Wl)
  const ushort_t* gbase = (wid == 0) ? Ah : (wid == 1) ? Al : (wid == 2) ? Wh : Wl;
  const int gr0 = (wid < 2) ? row0 : col0;

  // compute mapping
  const int wr = wid >> 1, wc = wid & 1;
  const int frow = lane & 15;
  const int kb = lane >> 4;
  const int abase = kb * 1024 + (wr * 64 + frow) * 8;
  const int bbase = kb * 1024 + (wc * 64 + frow) * 8;

  floatx4 acc[4][4];
  #pragma unroll
  for (int i = 0; i < 4; ++i)
    #pragma unroll
    for (int j = 0; j < 4; ++j) acc[i][j] = (floatx4){0.f, 0.f, 0.f, 0.f};

  // stage 8KB tile for this wave into lds[buf]: 8 x (64 lanes x 16B)
  #define STAGE_TILE(buf, kt) do {                                         \
    const ushort_t* gk_ = gbase + (size_t)gr0 * K + (kt);                  \
    ushort_t* lt_ = &lds[(buf)][wid * 4096];                               \
    _Pragma("unroll")                                                      \
    for (int i_ = 0; i_ < 8; ++i_) {                                       \
      const int kbs_ = i_ >> 1, mh_ = i_ & 1;                              \
      gload_lds16(gk_ + (size_t)(mh_ * 64 + lane) * K + kbs_ * 8,          \
                  lt_ + kbs_ * 1024 + mh_ * 512);                          \
    }                                                                      \
  } while (0)

  // prologue: fill buffer 0, wait for it
  STAGE_TILE(0, 0);
  __syncthreads();

  int cur = 0;
  for (int kt = 0; kt < K; kt += GBK) {
    // issue NEXT tile's loads first (stay in flight during compute below)
    if (kt + GBK < K) STAGE_TILE(cur ^ 1, kt + GBK);

    const ushort_t* L = lds[cur];
    short8v ah[4], al[4], bh[4], bl[4];
    #pragma unroll
    for (int mi = 0; mi < 4; ++mi) {
      ah[mi] = *(const short8v*)&L[0 * 4096 + abase + mi * 128];
      al[mi] = *(const short8v*)&L[1 * 4096 + abase + mi * 128];
    }
    #pragma unroll
    for (int nj = 0; nj < 4; ++nj) {
      bh[nj] = *(const short8v*)&L[2 * 4096 + bbase + nj * 128];
      bl[nj] = *(const short8v*)&L[3 * 4096 + bbase + nj * 128];
    }
    #pragma unroll
    for (int mi = 0; mi < 4; ++mi)
      #pragma unroll
      for (int nj = 0; nj < 4; ++nj) {
        acc[mi][nj] = __builtin_amdgcn_mfma_f32_16x16x32_bf16(ah[mi], bh[nj], acc[mi][nj], 0, 0, 0);
        acc[mi][nj] = __builtin_amdgcn_mfma_f32_16x16x32_bf16(ah[mi], bl[nj], acc[mi][nj], 0, 0, 0);
        acc[mi][nj] = __builtin_amdgcn_mfma_f32_16x16x32_bf16(al[mi], bh[nj], acc[mi][nj], 0, 0, 0);
      }

    // one barrier per K-step: drains the prefetch (latency already hidden by MFMAs)
    // and makes lds[cur^1] ready; also fences our ds_reads before next overwrite.
    __syncthreads();
    cur ^= 1;
  }
  #undef STAGE_TILE

  // epilogue: C/D layout col = lane&15, row = (lane>>4)*4 + reg  [m89-verified]
  const int rbase = row0 + wr * 64 + (lane >> 4) * 4;
  if (epi == 0) {
    #pragma unroll
    for (int nj = 0; nj < 4; ++nj) {
      const int col = col0 + wc * 64 + nj * 16 + frow;
      #pragma unroll
      for (int mi = 0; mi < 4; ++mi)
        #pragma unroll
        for (int r = 0; r < 4; ++r)
          C[(size_t)(rbase + mi * 16 + r) * N + col] = acc[mi][nj][r];
    }
  } else {
    #pragma unroll
    for (int nj = 0; nj < 4; ++nj) {
      const int col = col0 + wc * 64 + nj * 16 + frow;
      const float bcol = (col < 768) ? bias[col] : 0.f;
      #pragma unroll
      for (int mi = 0; mi < 4; ++mi) {
        #pragma unroll
        for (int r = 0; r < 4; ++r) {
          const int row = rbase + mi * 16 + r;
          const float v = acc[mi][nj][r];
          if (col < 768)      C[(size_t)row * N + col] = softplus_f(v + bcol);
          else if (col < 784) Bm[(size_t)row * D_STATEX + (col - 768)] = v;
          else if (col < 800) Cm[(size_t)row * D_STATEX + (col - 784)] = v;
        }
      }
    }
  }
}

// ---------------- depthwise causal conv (K=4) + SiLU -> bf16 hi/lo ----------------
__global__ __launch_bounds__(256) void conv_silu_k(
    const float* __restrict__ xs, const float* __restrict__ w,
    const float* __restrict__ bias, ushort_t* __restrict__ oh, ushort_t* __restrict__ ol)
{
  int idx = blockIdx.x * blockDim.x + threadIdx.x;  // over (B*T * D/4)
  const int D4 = D_MODELX / 4;
  int d4 = idx % D4, bt = idx / D4;
  int t = bt & (TSEQ - 1);
  int d = d4 * 4;

  float wv[4][4];
  #pragma unroll
  for (int i = 0; i < 4; ++i) *(float4*)wv[i] = *(const float4*)(w + (d + i) * KCONV);

  float accv[4];
  *(float4*)accv = *(const float4*)(bias + d);

  #pragma unroll
  for (int j = 0; j < KCONV; ++j) {
    int off = KCONV - 1 - j;
    if (t >= off) {
      float xv[4];
      *(float4*)xv = *(const float4*)(xs + (size_t)(bt - off) * D_MODELX + d);
      #pragma unroll
      for (int i = 0; i < 4; ++i) accv[i] = fmaf(xv[i], wv[i][j], accv[i]);
    }
  }
  ushort4 h, l;
  ushort_t hb;
  float s0 = accv[0] / (1.f + expf(-accv[0]));
  float s1 = accv[1] / (1.f + expf(-accv[1]));
  float s2 = accv[2] / (1.f + expf(-accv[2]));
  float s3 = accv[3] / (1.f + expf(-accv[3]));
  hb = f2bf(s0); h.x = hb; l.x = f2bf(s0 - bf2f(hb));
  hb = f2bf(s1); h.y = hb; l.y = f2bf(s1 - bf2f(hb));
  hb = f2bf(s2); h.z = hb; l.z = f2bf(s2 - bf2f(hb));
  hb = f2bf(s3); h.w = hb; l.w = f2bf(s3 - bf2f(hb));
  const size_t o4 = ((size_t)bt * D_MODELX + d) >> 2;
  ((ushort4*)oh)[o4] = h;
  ((ushort4*)ol)[o4] = l;
}

// ---------------- segmented selective scan ----------------
#define NSEG 32
#define LSEG 64
#define NSTATE (BSZ * D_MODELX * D_STATEX)   // 98304

__global__ __launch_bounds__(256) void scan_phase1(
    const float* __restrict__ x, const float* __restrict__ dt,
    const float* __restrict__ Bm, const float* __restrict__ A_log,
    float* __restrict__ P, float* __restrict__ Q)
{
  __shared__ float dt_s[LSEG][16], x_s[LSEG][16], B_s[LSEG][16];
  const int tiles_per_b = D_MODELX / 16;
  const int bid = blockIdx.x;
  const int dtile = bid % tiles_per_b;
  const int seg = (bid / tiles_per_b) % NSEG;
  const int b = bid / (tiles_per_b * NSEG);
  const int d0 = dtile * 16;
  const int tid = threadIdx.x;
  const int n = tid & 15, dd = tid >> 4;
  const int d = d0 + dd;

  const float A_dn = -__expf(A_log[d * D_STATEX + n]);

  const int ltt = tid >> 2;
  const int lc4 = (tid & 3) * 4;
  {
    const int t = seg * LSEG + ltt;
    const size_t base = ((size_t)b * TSEQ + t) * D_MODELX + d0 + lc4;
    const size_t bbase = ((size_t)b * TSEQ + t) * D_STATEX + lc4;
    *(float4*)&dt_s[ltt][lc4] = *(const float4*)(dt + base);
    *(float4*)&x_s[ltt][lc4]  = *(const float4*)(x + base);
    *(float4*)&B_s[ltt][lc4]  = *(const float4*)(Bm + bbase);
  }
  __syncthreads();

  float h = 0.f, Pp = 1.f;
  #pragma unroll 8
  for (int tt = 0; tt < LSEG; ++tt) {
    float dtv = dt_s[tt][dd];
    float xv  = x_s[tt][dd];
    float bv  = B_s[tt][n];
    float a   = __expf(A_dn * dtv);
    Pp *= a;
    h = fmaf(h, a, xv * dtv * bv);
  }
  const size_t g = ((size_t)b * D_MODELX + d0) * D_STATEX + tid;
  P[(size_t)seg * NSTATE + g] = Pp;
  Q[(size_t)seg * NSTATE + g] = h;
}

__global__ __launch_bounds__(256) void scan_combine(
    float* __restrict__ P, float* __restrict__ Q)
{
  const size_t g = (size_t)blockIdx.x * 256 + threadIdx.x;
  float H = 0.f;
  #pragma unroll
  for (int s = 0; s < NSEG; ++s) {
    float p = P[(size_t)s * NSTATE + g];
    float q = Q[(size_t)s * NSTATE + g];
    P[(size_t)s * NSTATE + g] = H;
    H = fmaf(p, H, q);
  }
}

__global__ __launch_bounds__(256) void scan_phase2(
    const float* __restrict__ x, const float* __restrict__ dt,
    const float* __restrict__ Bm, const float* __restrict__ Cm,
    const float* __restrict__ A_log, const float* __restrict__ Dp,
    const float* __restrict__ Hinit, float* __restrict__ y)
{
  __shared__ float dt_s[LSEG][16], x_s[LSEG][16], B_s[LSEG][16], C_s[LSEG][16], y_s[LSEG][16];
  const int tiles_per_b = D_MODELX / 16;
  const int bid = blockIdx.x;
  const int dtile = bid % tiles_per_b;
  const int seg = (bid / tiles_per_b) % NSEG;
  const int b = bid / (tiles_per_b * NSEG);
  const int d0 = dtile * 16;
  const int tid = threadIdx.x;
  const int n = tid & 15, dd = tid >> 4;
  const int d = d0 + dd;

  const float A_dn = -__expf(A_log[d * D_STATEX + n]);
  const size_t g = ((size_t)b * D_MODELX + d0) * D_STATEX + tid;
  float h = Hinit[(size_t)seg * NSTATE + g];

  const int ltt = tid >> 2;
  const int lc4 = (tid & 3) * 4;
  float dv[4];
  *(float4*)dv = *(const float4*)(Dp + d0 + lc4);

  const int t = seg * LSEG + ltt;
  const size_t base = ((size_t)b * TSEQ + t) * D_MODELX + d0 + lc4;
  {
    const size_t bbase = ((size_t)b * TSEQ + t) * D_STATEX + lc4;
    *(float4*)&dt_s[ltt][lc4] = *(const float4*)(dt + base);
    *(float4*)&x_s[ltt][lc4]  = *(const float4*)(x + base);
    *(float4*)&B_s[ltt][lc4]  = *(const float4*)(Bm + bbase);
    *(float4*)&C_s[ltt][lc4]  = *(const float4*)(Cm + bbase);
  }
  __syncthreads();

  #pragma unroll 4
  for (int tt = 0; tt < LSEG; ++tt) {
    float dtv = dt_s[tt][dd];
    float xv  = x_s[tt][dd];
    float bv  = B_s[tt][n];
    float cv  = C_s[tt][n];
    float a   = __expf(A_dn * dtv);
    h = fmaf(h, a, xv * dtv * bv);
    float p = h * cv;
    p += __shfl_xor(p, 1);
    p += __shfl_xor(p, 2);
    p += __shfl_xor(p, 4);
    p += __shfl_xor(p, 8);
    if (n == 0) y_s[tt][dd] = p;
  }
  __syncthreads();

  float yv[4], xv[4];
  *(float4*)yv = *(const float4*)&y_s[ltt][lc4];
  *(float4*)xv = *(const float4*)&x_s[ltt][lc4];
  #pragma unroll
  for (int i = 0; i < 4; ++i) yv[i] = fmaf(xv[i], dv[i], yv[i]);
  *(float4*)(y + base) = *(const float4*)yv;
}

extern "C" void kernel_launch(void* const* d_in, const int* in_sizes, int n_in,
                              void* d_out, int out_size, void* d_ws, size_t ws_size,
                              hipStream_t stream) {
  const float* x      = (const float*)d_in[0];
  const float* W_in   = (const float*)d_in[1];
  const float* conv_w = (const float*)d_in[2];
  const float* conv_b = (const float*)d_in[3];
  const float* W_dt   = (const float*)d_in[4];
  const float* b_dt   = (const float*)d_in[5];
  const float* A_log  = (const float*)d_in[6];
  const float* D_par  = (const float*)d_in[7];
  const float* W_B    = (const float*)d_in[8];
  const float* W_C    = (const float*)d_in[9];
  float* y = (float*)d_out;

  const int M = BSZ * TSEQ;              // 16384
  const size_t MD = (size_t)M * D_MODELX;
  const size_t WD = (size_t)D_MODELX * D_MODELX;
  const size_t WCAT = (size_t)NCAT * D_MODELX;

  char* p = (char*)d_ws;
  float* x_ssm = (float*)p;       p += MD * 4;           // GEMM1 out; later dtb
  ushort_t* xh = (ushort_t*)p;                            // region1: xh|xl -> xch|xcl -> P|Q
  ushort_t* xl = xh + MD;         p += MD * 2 * 2;
  ushort_t* Wh_in = (ushort_t*)p; p += WD * 2;
  ushort_t* Wl_in = (ushort_t*)p; p += WD * 2;
  ushort_t* Wh_ct = (ushort_t*)p; p += WCAT * 2;
  ushort_t* Wl_ct = (ushort_t*)p; p += WCAT * 2;
  float* Bm = (float*)p;          p += (size_t)M * D_STATEX * 4;
  float* Cm = (float*)p;          p += (size_t)M * D_STATEX * 4;

  // 0) splits
  split_hl<<<(int)(MD / 4 / 256), 256, 0, stream>>>(x, xh, xl, (int)(MD / 4));
  split_hl<<<(int)(WD / 4 / 256), 256, 0, stream>>>(W_in, Wh_in, Wl_in, (int)(WD / 4));  // rows :768 only
  split_cat<<<(int)((WCAT / 4 + 255) / 256), 256, 0, stream>>>(W_dt, W_B, W_C, Wh_ct, Wl_ct);

  // 1) x_ssm = x @ W_in[:768].T  (bf16x3 MFMA, 2-phase pipelined)
  gemm_bf16x3<<<dim3(D_MODELX / GBN, M / GBM), 256, 0, stream>>>(
      xh, xl, Wh_in, Wl_in, x_ssm, M, D_MODELX, D_MODELX, nullptr, 0, nullptr, nullptr);

  // 2) conv + SiLU -> bf16 hi/lo (overwrites xh/xl region — dead after GEMM1)
  ushort_t* xch = xh;
  ushort_t* xcl = xl;
  conv_silu_k<<<(int)(M * (D_MODELX / 4)) / 256, 256, 0, stream>>>(
      x_ssm, conv_w, conv_b, xch, xcl);

  // 3) fused: dt = softplus(x_conv @ W_dt.T + b_dt); Bm = x_conv @ W_B.T; Cm = x_conv @ W_C.T
  float* dtb = x_ssm;
  gemm_bf16x3<<<dim3(NCAT / GBN, M / GBM), 256, 0, stream>>>(
      xch, xcl, Wh_ct, Wl_ct, dtb, M, D_MODELX, D_MODELX, b_dt, 2, Bm, Cm);

  // 4) segmented scan (P/Q overwrite xch/xcl region — dead after fused GEMM)
  float* P = (float*)xh;
  float* Q = P + (size_t)NSEG * NSTATE;
  const int nblk = BSZ * (D_MODELX / 16) * NSEG;
  scan_phase1<<<nblk, 256, 0, stream>>>(x, dtb, Bm, A_log, P, Q);
  scan_combine<<<NSTATE / 256, 256, 0, stream>>>(P, Q);
  scan_phase2<<<nblk, 256, 0, stream>>>(x, dtb, Bm, Cm, A_log, D_par, P, y);
}

// Round 13
// 821.401 us; speedup vs baseline: 1.0184x; 1.0184x over previous
//
#include <hip/hip_runtime.h>
#include <hip/hip_bf16.h>
#include <cstdint>

#define D_MODELX 768
#define D_STATEX 16
#define TSEQ 2048
#define BSZ 8
#define KCONV 4
#define NCAT 896          // 768 (dt) + 16 (B) + 16 (C) + 96 pad, = 7*128

typedef unsigned short ushort_t;
typedef __attribute__((ext_vector_type(8))) short short8v;   // 8 bf16 = 4 VGPR
typedef __attribute__((ext_vector_type(4))) float floatx4;

__device__ __forceinline__ unsigned short f2bf(float f) {   // RNE truncate to bf16
  unsigned int u = __float_as_uint(f);
  unsigned int r = u + 0x7FFFu + ((u >> 16) & 1u);
  return (unsigned short)(r >> 16);
}
__device__ __forceinline__ float bf2f(unsigned short s) {
  return __uint_as_float(((unsigned int)s) << 16);
}
__device__ __forceinline__ float softplus_f(float v) {
  return fmaxf(v, 0.f) + log1pf(expf(-fabsf(v)));
}
__device__ __forceinline__ void gload_lds16(const void* gsrc, void* ldst) {
  __builtin_amdgcn_global_load_lds(
      (const __attribute__((address_space(1))) unsigned int*)gsrc,
      (__attribute__((address_space(3))) unsigned int*)ldst, 16, 0, 0);
}

// ---------------- split f32 -> bf16 hi/lo ----------------
__global__ __launch_bounds__(256) void split_hl(
    const float* __restrict__ in, ushort_t* __restrict__ hi,
    ushort_t* __restrict__ lo, int n4)
{
  int i = blockIdx.x * 256 + threadIdx.x;
  if (i >= n4) return;
  float4 v = ((const float4*)in)[i];
  ushort4 h, l;
  ushort_t hb;
  hb = f2bf(v.x); h.x = hb; l.x = f2bf(v.x - bf2f(hb));
  hb = f2bf(v.y); h.y = hb; l.y = f2bf(v.y - bf2f(hb));
  hb = f2bf(v.z); h.z = hb; l.z = f2bf(v.z - bf2f(hb));
  hb = f2bf(v.w); h.w = hb; l.w = f2bf(v.w - bf2f(hb));
  ((ushort4*)hi)[i] = h;
  ((ushort4*)lo)[i] = l;
}

// ---- build concat weight [896][768]: rows 0..767 = W_dt, 768..783 = W_B, 784..799 = W_C, rest 0
__global__ __launch_bounds__(256) void split_cat(
    const float* __restrict__ Wdt, const float* __restrict__ WB,
    const float* __restrict__ WC, ushort_t* __restrict__ hi, ushort_t* __restrict__ lo)
{
  int i = blockIdx.x * 256 + threadIdx.x;          // over NCAT*768/4
  if (i >= NCAT * D_MODELX / 4) return;
  const int row = i / (D_MODELX / 4);
  const int c = (i % (D_MODELX / 4)) * 4;
  float4 v;
  if (row < 768)       v = *(const float4*)(Wdt + (size_t)row * D_MODELX + c);
  else if (row < 784)  v = *(const float4*)(WB + (size_t)(row - 768) * D_MODELX + c);
  else if (row < 800)  v = *(const float4*)(WC + (size_t)(row - 784) * D_MODELX + c);
  else                 v = make_float4(0.f, 0.f, 0.f, 0.f);
  ushort4 h, l;
  ushort_t hb;
  hb = f2bf(v.x); h.x = hb; l.x = f2bf(v.x - bf2f(hb));
  hb = f2bf(v.y); h.y = hb; l.y = f2bf(v.y - bf2f(hb));
  hb = f2bf(v.z); h.z = hb; l.z = f2bf(v.z - bf2f(hb));
  hb = f2bf(v.w); h.w = hb; l.w = f2bf(v.w - bf2f(hb));
  ((ushort4*)hi)[i] = h;
  ((ushort4*)lo)[i] = l;
}

// ---------------- bf16x3 MFMA GEMM: C[M,N] = (Ah+Al)[M,K] @ (Wh+Wl)[NW,K]^T ----------------
// 128x128 tile, BK=32, 4 waves (2x2 of 64x64), single-buffer 2-barrier loop (round-10
// measured baseline; dbuf regressed in round 12 — barrier drains vmcnt(0) regardless).
// T1 bijective XCD swizzle: consecutive-dispatch blocks share A-rows; round-robin XCD
// assignment scattered them across XCDs (FETCH 225MB vs 55MB ideal). Remap so each XCD
// owns contiguous row-groups x all column-tiles -> A-tile L2-resident after first fetch.
// epi==0: plain store to C[M,N]. epi==2: mamba epilogue (dt softplus+bias / Bm / Cm split).
#define GBM 128
#define GBN 128
#define GBK 32

__global__ __launch_bounds__(256) void gemm_bf16x3(
    const ushort_t* __restrict__ Ah, const ushort_t* __restrict__ Al,
    const ushort_t* __restrict__ Wh, const ushort_t* __restrict__ Wl,
    float* __restrict__ C, int M, int N, int K,
    const float* __restrict__ bias, int epi,
    float* __restrict__ Bm, float* __restrict__ Cm)
{
  __shared__ ushort_t lds[4 * 4096];   // 32 KB
  const int tid = threadIdx.x;
  const int wid = tid >> 6;            // 0..3
  const int lane = tid & 63;

  // T1 XCD-aware bijective swizzle (nwg = 768 or 896, both % 8 == 0):
  // orig%8 = XCD (round-robin dispatch); give each XCD a contiguous swz range so the
  // gridDim.x column-tiles of each row-group co-reside on one XCD's L2.
  const int gx = gridDim.x;
  const int nwg = gx * gridDim.y;
  const int orig = blockIdx.y * gx + blockIdx.x;
  const int swz = (orig & 7) * (nwg >> 3) + (orig >> 3);
  const int row0 = (swz / gx) * GBM;
  const int col0 = (swz % gx) * GBN;

  // staging: wave wid owns tile wid (0:Ah 1:Al 2:Wh 3:Wl)
  const ushort_t* gbase = (wid == 0) ? Ah : (wid == 1) ? Al : (wid == 2) ? Wh : Wl;
  const int gr0 = (wid < 2) ? row0 : col0;
  ushort_t* lt = &lds[wid * 4096];

  // compute mapping
  const int wr = wid >> 1, wc = wid & 1;
  const int frow = lane & 15;
  const int kb = lane >> 4;
  const int abase = kb * 1024 + (wr * 64 + frow) * 8;
  const int bbase = kb * 1024 + (wc * 64 + frow) * 8;

  floatx4 acc[4][4];
  #pragma unroll
  for (int i = 0; i < 4; ++i)
    #pragma unroll
    for (int j = 0; j < 4; ++j) acc[i][j] = (floatx4){0.f, 0.f, 0.f, 0.f};

  for (int kt = 0; kt < K; kt += GBK) {
    // stage 8KB tile for this wave: 8 x (64 lanes x 16B)
    const ushort_t* gk = gbase + (size_t)gr0 * K + kt;
    #pragma unroll
    for (int i = 0; i < 8; ++i) {
      const int kbs = i >> 1, mh = i & 1;
      gload_lds16(gk + (size_t)(mh * 64 + lane) * K + kbs * 8,
                  lt + kbs * 1024 + mh * 512);
    }
    __syncthreads();   // compiler drains vmcnt before barrier

    short8v ah[4], al[4], bh[4], bl[4];
    #pragma unroll
    for (int mi = 0; mi < 4; ++mi) {
      ah[mi] = *(const short8v*)&lds[0 * 4096 + abase + mi * 128];
      al[mi] = *(const short8v*)&lds[1 * 4096 + abase + mi * 128];
    }
    #pragma unroll
    for (int nj = 0; nj < 4; ++nj) {
      bh[nj] = *(const short8v*)&lds[2 * 4096 + bbase + nj * 128];
      bl[nj] = *(const short8v*)&lds[3 * 4096 + bbase + nj * 128];
    }
    #pragma unroll
    for (int mi = 0; mi < 4; ++mi)
      #pragma unroll
      for (int nj = 0; nj < 4; ++nj) {
        acc[mi][nj] = __builtin_amdgcn_mfma_f32_16x16x32_bf16(ah[mi], bh[nj], acc[mi][nj], 0, 0, 0);
        acc[mi][nj] = __builtin_amdgcn_mfma_f32_16x16x32_bf16(ah[mi], bl[nj], acc[mi][nj], 0, 0, 0);
        acc[mi][nj] = __builtin_amdgcn_mfma_f32_16x16x32_bf16(al[mi], bh[nj], acc[mi][nj], 0, 0, 0);
      }
    __syncthreads();
  }

  // epilogue: C/D layout col = lane&15, row = (lane>>4)*4 + reg  [m89-verified]
  const int rbase = row0 + wr * 64 + (lane >> 4) * 4;
  if (epi == 0) {
    #pragma unroll
    for (int nj = 0; nj < 4; ++nj) {
      const int col = col0 + wc * 64 + nj * 16 + frow;
      #pragma unroll
      for (int mi = 0; mi < 4; ++mi)
        #pragma unroll
        for (int r = 0; r < 4; ++r)
          C[(size_t)(rbase + mi * 16 + r) * N + col] = acc[mi][nj][r];
    }
  } else {
    #pragma unroll
    for (int nj = 0; nj < 4; ++nj) {
      const int col = col0 + wc * 64 + nj * 16 + frow;
      const float bcol = (col < 768) ? bias[col] : 0.f;
      #pragma unroll
      for (int mi = 0; mi < 4; ++mi) {
        #pragma unroll
        for (int r = 0; r < 4; ++r) {
          const int row = rbase + mi * 16 + r;
          const float v = acc[mi][nj][r];
          if (col < 768)      C[(size_t)row * N + col] = softplus_f(v + bcol);
          else if (col < 784) Bm[(size_t)row * D_STATEX + (col - 768)] = v;
          else if (col < 800) Cm[(size_t)row * D_STATEX + (col - 784)] = v;
        }
      }
    }
  }
}

// ---------------- depthwise causal conv (K=4) + SiLU -> bf16 hi/lo ----------------
__global__ __launch_bounds__(256) void conv_silu_k(
    const float* __restrict__ xs, const float* __restrict__ w,
    const float* __restrict__ bias, ushort_t* __restrict__ oh, ushort_t* __restrict__ ol)
{
  int idx = blockIdx.x * blockDim.x + threadIdx.x;  // over (B*T * D/4)
  const int D4 = D_MODELX / 4;
  int d4 = idx % D4, bt = idx / D4;
  int t = bt & (TSEQ - 1);
  int d = d4 * 4;

  float wv[4][4];
  #pragma unroll
  for (int i = 0; i < 4; ++i) *(float4*)wv[i] = *(const float4*)(w + (d + i) * KCONV);

  float accv[4];
  *(float4*)accv = *(const float4*)(bias + d);

  #pragma unroll
  for (int j = 0; j < KCONV; ++j) {
    int off = KCONV - 1 - j;
    if (t >= off) {
      float xv[4];
      *(float4*)xv = *(const float4*)(xs + (size_t)(bt - off) * D_MODELX + d);
      #pragma unroll
      for (int i = 0; i < 4; ++i) accv[i] = fmaf(xv[i], wv[i][j], accv[i]);
    }
  }
  ushort4 h, l;
  ushort_t hb;
  float s0 = accv[0] / (1.f + expf(-accv[0]));
  float s1 = accv[1] / (1.f + expf(-accv[1]));
  float s2 = accv[2] / (1.f + expf(-accv[2]));
  float s3 = accv[3] / (1.f + expf(-accv[3]));
  hb = f2bf(s0); h.x = hb; l.x = f2bf(s0 - bf2f(hb));
  hb = f2bf(s1); h.y = hb; l.y = f2bf(s1 - bf2f(hb));
  hb = f2bf(s2); h.z = hb; l.z = f2bf(s2 - bf2f(hb));
  hb = f2bf(s3); h.w = hb; l.w = f2bf(s3 - bf2f(hb));
  const size_t o4 = ((size_t)bt * D_MODELX + d) >> 2;
  ((ushort4*)oh)[o4] = h;
  ((ushort4*)ol)[o4] = l;
}

// ---------------- segmented selective scan ----------------
#define NSEG 32
#define LSEG 64
#define NSTATE (BSZ * D_MODELX * D_STATEX)   // 98304

__global__ __launch_bounds__(256) void scan_phase1(
    const float* __restrict__ x, const float* __restrict__ dt,
    const float* __restrict__ Bm, const float* __restrict__ A_log,
    float* __restrict__ P, float* __restrict__ Q)
{
  __shared__ float dt_s[LSEG][16], x_s[LSEG][16], B_s[LSEG][16];
  const int tiles_per_b = D_MODELX / 16;
  const int bid = blockIdx.x;
  const int dtile = bid % tiles_per_b;
  const int seg = (bid / tiles_per_b) % NSEG;
  const int b = bid / (tiles_per_b * NSEG);
  const int d0 = dtile * 16;
  const int tid = threadIdx.x;
  const int n = tid & 15, dd = tid >> 4;
  const int d = d0 + dd;

  const float A_dn = -__expf(A_log[d * D_STATEX + n]);

  const int ltt = tid >> 2;
  const int lc4 = (tid & 3) * 4;
  {
    const int t = seg * LSEG + ltt;
    const size_t base = ((size_t)b * TSEQ + t) * D_MODELX + d0 + lc4;
    const size_t bbase = ((size_t)b * TSEQ + t) * D_STATEX + lc4;
    *(float4*)&dt_s[ltt][lc4] = *(const float4*)(dt + base);
    *(float4*)&x_s[ltt][lc4]  = *(const float4*)(x + base);
    *(float4*)&B_s[ltt][lc4]  = *(const float4*)(Bm + bbase);
  }
  __syncthreads();

  float h = 0.f, Pp = 1.f;
  #pragma unroll 8
  for (int tt = 0; tt < LSEG; ++tt) {
    float dtv = dt_s[tt][dd];
    float xv  = x_s[tt][dd];
    float bv  = B_s[tt][n];
    float a   = __expf(A_dn * dtv);
    Pp *= a;
    h = fmaf(h, a, xv * dtv * bv);
  }
  const size_t g = ((size_t)b * D_MODELX + d0) * D_STATEX + tid;
  P[(size_t)seg * NSTATE + g] = Pp;
  Q[(size_t)seg * NSTATE + g] = h;
}

__global__ __launch_bounds__(256) void scan_combine(
    float* __restrict__ P, float* __restrict__ Q)
{
  const size_t g = (size_t)blockIdx.x * 256 + threadIdx.x;
  float H = 0.f;
  #pragma unroll
  for (int s = 0; s < NSEG; ++s) {
    float p = P[(size_t)s * NSTATE + g];
    float q = Q[(size_t)s * NSTATE + g];
    P[(size_t)s * NSTATE + g] = H;
    H = fmaf(p, H, q);
  }
}

__global__ __launch_bounds__(256) void scan_phase2(
    const float* __restrict__ x, const float* __restrict__ dt,
    const float* __restrict__ Bm, const float* __restrict__ Cm,
    const float* __restrict__ A_log, const float* __restrict__ Dp,
    const float* __restrict__ Hinit, float* __restrict__ y)
{
  __shared__ float dt_s[LSEG][16], x_s[LSEG][16], B_s[LSEG][16], C_s[LSEG][16], y_s[LSEG][16];
  const int tiles_per_b = D_MODELX / 16;
  const int bid = blockIdx.x;
  const int dtile = bid % tiles_per_b;
  const int seg = (bid / tiles_per_b) % NSEG;
  const int b = bid / (tiles_per_b * NSEG);
  const int d0 = dtile * 16;
  const int tid = threadIdx.x;
  const int n = tid & 15, dd = tid >> 4;
  const int d = d0 + dd;

  const float A_dn = -__expf(A_log[d * D_STATEX + n]);
  const size_t g = ((size_t)b * D_MODELX + d0) * D_STATEX + tid;
  float h = Hinit[(size_t)seg * NSTATE + g];

  const int ltt = tid >> 2;
  const int lc4 = (tid & 3) * 4;
  float dv[4];
  *(float4*)dv = *(const float4*)(Dp + d0 + lc4);

  const int t = seg * LSEG + ltt;
  const size_t base = ((size_t)b * TSEQ + t) * D_MODELX + d0 + lc4;
  {
    const size_t bbase = ((size_t)b * TSEQ + t) * D_STATEX + lc4;
    *(float4*)&dt_s[ltt][lc4] = *(const float4*)(dt + base);
    *(float4*)&x_s[ltt][lc4]  = *(const float4*)(x + base);
    *(float4*)&B_s[ltt][lc4]  = *(const float4*)(Bm + bbase);
    *(float4*)&C_s[ltt][lc4]  = *(const float4*)(Cm + bbase);
  }
  __syncthreads();

  #pragma unroll 4
  for (int tt = 0; tt < LSEG; ++tt) {
    float dtv = dt_s[tt][dd];
    float xv  = x_s[tt][dd];
    float bv  = B_s[tt][n];
    float cv  = C_s[tt][n];
    float a   = __expf(A_dn * dtv);
    h = fmaf(h, a, xv * dtv * bv);
    float p = h * cv;
    p += __shfl_xor(p, 1);
    p += __shfl_xor(p, 2);
    p += __shfl_xor(p, 4);
    p += __shfl_xor(p, 8);
    if (n == 0) y_s[tt][dd] = p;
  }
  __syncthreads();

  float yv[4], xv[4];
  *(float4*)yv = *(const float4*)&y_s[ltt][lc4];
  *(float4*)xv = *(const float4*)&x_s[ltt][lc4];
  #pragma unroll
  for (int i = 0; i < 4; ++i) yv[i] = fmaf(xv[i], dv[i], yv[i]);
  *(float4*)(y + base) = *(const float4*)yv;
}

extern "C" void kernel_launch(void* const* d_in, const int* in_sizes, int n_in,
                              void* d_out, int out_size, void* d_ws, size_t ws_size,
                              hipStream_t stream) {
  const float* x      = (const float*)d_in[0];
  const float* W_in   = (const float*)d_in[1];
  const float* conv_w = (const float*)d_in[2];
  const float* conv_b = (const float*)d_in[3];
  const float* W_dt   = (const float*)d_in[4];
  const float* b_dt   = (const float*)d_in[5];
  const float* A_log  = (const float*)d_in[6];
  const float* D_par  = (const float*)d_in[7];
  const float* W_B    = (const float*)d_in[8];
  const float* W_C    = (const float*)d_in[9];
  float* y = (float*)d_out;

  const int M = BSZ * TSEQ;              // 16384
  const size_t MD = (size_t)M * D_MODELX;
  const size_t WD = (size_t)D_MODELX * D_MODELX;
  const size_t WCAT = (size_t)NCAT * D_MODELX;

  char* p = (char*)d_ws;
  float* x_ssm = (float*)p;       p += MD * 4;           // GEMM1 out; later dtb
  ushort_t* xh = (ushort_t*)p;                            // region1: xh|xl -> xch|xcl -> P|Q
  ushort_t* xl = xh + MD;         p += MD * 2 * 2;
  ushort_t* Wh_in = (ushort_t*)p; p += WD * 2;
  ushort_t* Wl_in = (ushort_t*)p; p += WD * 2;
  ushort_t* Wh_ct = (ushort_t*)p; p += WCAT * 2;
  ushort_t* Wl_ct = (ushort_t*)p; p += WCAT * 2;
  float* Bm = (float*)p;          p += (size_t)M * D_STATEX * 4;
  float* Cm = (float*)p;          p += (size_t)M * D_STATEX * 4;

  // 0) splits
  split_hl<<<(int)(MD / 4 / 256), 256, 0, stream>>>(x, xh, xl, (int)(MD / 4));
  split_hl<<<(int)(WD / 4 / 256), 256, 0, stream>>>(W_in, Wh_in, Wl_in, (int)(WD / 4));  // rows :768 only
  split_cat<<<(int)((WCAT / 4 + 255) / 256), 256, 0, stream>>>(W_dt, W_B, W_C, Wh_ct, Wl_ct);

  // 1) x_ssm = x @ W_in[:768].T  (bf16x3 MFMA, XCD-swizzled)
  gemm_bf16x3<<<dim3(D_MODELX / GBN, M / GBM), 256, 0, stream>>>(
      xh, xl, Wh_in, Wl_in, x_ssm, M, D_MODELX, D_MODELX, nullptr, 0, nullptr, nullptr);

  // 2) conv + SiLU -> bf16 hi/lo (overwrites xh/xl region — dead after GEMM1)
  ushort_t* xch = xh;
  ushort_t* xcl = xl;
  conv_silu_k<<<(int)(M * (D_MODELX / 4)) / 256, 256, 0, stream>>>(
      x_ssm, conv_w, conv_b, xch, xcl);

  // 3) fused: dt = softplus(x_conv @ W_dt.T + b_dt); Bm = x_conv @ W_B.T; Cm = x_conv @ W_C.T
  float* dtb = x_ssm;
  gemm_bf16x3<<<dim3(NCAT / GBN, M / GBM), 256, 0, stream>>>(
      xch, xcl, Wh_ct, Wl_ct, dtb, M, D_MODELX, D_MODELX, b_dt, 2, Bm, Cm);

  // 4) segmented scan (P/Q overwrite xch/xcl region — dead after fused GEMM)
  float* P = (float*)xh;
  float* Q = P + (size_t)NSEG * NSTATE;
  const int nblk = BSZ * (D_MODELX / 16) * NSEG;
  scan_phase1<<<nblk, 256, 0, stream>>>(x, dtb, Bm, A_log, P, Q);
  scan_combine<<<NSTATE / 256, 256, 0, stream>>>(P, Q);
  scan_phase2<<<nblk, 256, 0, stream>>>(x, dtb, Bm, Cm, A_log, D_par, P, y);
}